// Round 15
// baseline (241.111 us; speedup 1.0000x reference)
//
#include <hip/hip_runtime.h>
#include <math.h>

#define BINS 128

// ---------------- ws layout (float units) ----------------
// [0, 8192)        p       pooled means (B=2, C=64, sp=64)
// [8192, 8320)     s       sigmoid gate (2, 64)
// [8448, 8450)     mm      mapped uints {min, max}
// [8456, 8584)     ghist   uint[128]

__device__ __forceinline__ unsigned mapf(float f) {
    unsigned u = __float_as_uint(f);
    return (u & 0x80000000u) ? ~u : (u | 0x80000000u);
}
__device__ __forceinline__ float unmapf(unsigned m) {
    unsigned u = (m & 0x80000000u) ? (m & 0x7FFFFFFFu) : ~m;
    return __uint_as_float(u);
}
__device__ __forceinline__ float sel4(float g0, float g1, float g2, float g3, int k) {
    float a = (k & 1) ? g1 : g0;
    float b = (k & 1) ? g3 : g2;
    return (k & 2) ? b : a;
}
// axis coord for trilinear upsample (align_corners=False, 4 -> 64)
__device__ __forceinline__ void axgate(int v, int& lo, int& hi, float& fr) {
    float c = ((float)v + 0.5f) * 0.0625f - 0.5f;
    c = fminf(fmaxf(c, 0.0f), 3.0f);
    int l = (int)floorf(c);
    lo = l; hi = min(l + 1, 3); fr = c - (float)l;
}

// ---- K1: adaptive avg pool (R1-proven). 512 blocks, one 16x64x64 slab each. ----
__global__ __launch_bounds__(256) void pool_kernel(const float* __restrict__ x,
                                                   float* __restrict__ p) {
    const int blk = blockIdx.x;
    const int t = threadIdx.x;
    const float4* xb = (const float4*)x + (size_t)blk * 16384;
    float acc0 = 0.f, acc1 = 0.f, acc2 = 0.f, acc3 = 0.f;
    for (int n = 0; n < 64; n += 4) {
        float4 v0 = xb[(n + 0) * 256 + t]; acc0 += (v0.x + v0.y) + (v0.z + v0.w);
        float4 v1 = xb[(n + 1) * 256 + t]; acc1 += (v1.x + v1.y) + (v1.z + v1.w);
        float4 v2 = xb[(n + 2) * 256 + t]; acc2 += (v2.x + v2.y) + (v2.z + v2.w);
        float4 v3 = xb[(n + 3) * 256 + t]; acc3 += (v3.x + v3.y) + (v3.z + v3.w);
    }
    #pragma unroll
    for (int m = 0; m < 4; ++m) {
        int mask = (m == 0) ? 1 : (m == 1) ? 2 : (m == 2) ? 16 : 32;
        acc0 += __shfl_xor(acc0, mask);
        acc1 += __shfl_xor(acc1, mask);
        acc2 += __shfl_xor(acc2, mask);
        acc3 += __shfl_xor(acc3, mask);
    }
    __shared__ float red[64];
    const int lane = t & 63, wave = t >> 6;
    if (lane < 16 && (lane & 3) == 0) {
        const int pw = lane >> 2;
        red[(0 * 4 + pw) * 4 + wave] = acc0;
        red[(1 * 4 + pw) * 4 + wave] = acc1;
        red[(2 * 4 + pw) * 4 + wave] = acc2;
        red[(3 * 4 + pw) * 4 + wave] = acc3;
    }
    __syncthreads();
    if (t < 16)
        p[blk * 16 + t] = (red[t * 4 + 0] + red[t * 4 + 1] + red[t * 4 + 2] + red[t * 4 + 3]) * (1.0f / 4096.0f);
}

// ---- K2: w1 conv + InstanceNorm + GELU + w2 conv + sigmoid + init (R1-proven) ----
__global__ __launch_bounds__(1024) void mid_kernel(const float* __restrict__ p,
                                                   const float* __restrict__ w1,
                                                   const float* __restrict__ w2,
                                                   float* __restrict__ s_out,
                                                   unsigned* __restrict__ mm,
                                                   unsigned* __restrict__ hist) {
    __shared__ float hs[2 * 8 * 64];
    const int t = threadIdx.x;
    const int b = t >> 9, cm = (t >> 6) & 7, sp = t & 63;
    float h = 0.f;
    const float* pb = p + b * 64 * 64 + sp;
    const float* w1r = w1 + cm * 64;
    for (int c = 0; c < 64; ++c) h += w1r[c] * pb[c * 64];
    float s1 = h;
    #pragma unroll
    for (int m = 1; m <= 32; m <<= 1) s1 += __shfl_xor(s1, m);
    const float mu = s1 * (1.0f / 64.0f);
    float d = h - mu;
    float s2 = d * d;
    #pragma unroll
    for (int m = 1; m <= 32; m <<= 1) s2 += __shfl_xor(s2, m);
    const float var = s2 * (1.0f / 64.0f);
    const float hn = d / sqrtf(var + 1e-5f);
    hs[(b * 8 + cm) * 64 + sp] = 0.5f * hn * (1.0f + erff(hn * 0.70710678118654752440f));
    __syncthreads();
    if (t < 128) {
        const int bb = t >> 6, ss = t & 63;
        float acc = 0.f;
        #pragma unroll
        for (int c = 0; c < 8; ++c) acc += w2[c] * hs[(bb * 8 + c) * 64 + ss];
        s_out[t] = 1.0f / (1.0f + expf(-acc));
    }
    if (t == 0) { mm[0] = 0xFFFFFFFFu; mm[1] = 0u; }
    if (t >= 128 && t < 256) hist[t - 128] = 0u;
}

// ---------- shared machinery for the streaming passes (R9-proven) ----------
// 512 blocks, 4 chunks/block, chunk = 4096 float4 = one (b,c,dq) quad.

#define PASS_SETUP()                                                                  \
    const int t = threadIdx.x;                                                        \
    const int bid = blockIdx.x;                                                       \
    const int cbase = (bid & 7) * 256 + (bid >> 3) * 4;                               \
    const int b = cbase >> 10;                                                        \
    if (t < 64) ls64[t] = s[b * 64 + t];                                              \
    int wl0, wh0, wl1, wh1, wl2, wh2, wl3, wh3;                                       \
    float fw0, fw1, fw2, fw3;                                                         \
    {                                                                                 \
        const int wb = (t & 15) * 4;                                                  \
        axgate(wb + 0, wl0, wh0, fw0); axgate(wb + 1, wl1, wh1, fw1);                 \
        axgate(wb + 2, wl2, wh2, fw2); axgate(wb + 3, wl3, wh3, fw3);                 \
    }                                                                                 \
    int hlL, hhL; float fhL; axgate(t & 63, hlL, hhL, fhL);                           \
    const int rbase = t >> 4;

#define CHUNK_HEAD(IT)                                                                \
    const int swz = cbase + (IT);                                                     \
    const int dq = swz & 15;                                                          \
    const float4* xp = (const float4*)x + (size_t)swz * 4096;                         \
    __syncthreads();                                                                  \
    {                                                                                 \
        int dl, dh2; float fd; axgate(dq * 4 + (t >> 6), dl, dh2, fd);                \
        const float w00 = (1.f - fd) * (1.f - fhL), w01 = (1.f - fd) * fhL;           \
        const float w10 = fd * (1.f - fhL), w11 = fd * fhL;                           \
        const int i00 = dl * 16 + hlL * 4, i01 = dl * 16 + hhL * 4;                   \
        const int i10 = dh2 * 16 + hlL * 4, i11 = dh2 * 16 + hhL * 4;                 \
        float g0 = w00 * ls64[i00 + 0] + w01 * ls64[i01 + 0] + w10 * ls64[i10 + 0] + w11 * ls64[i11 + 0]; \
        float g1 = w00 * ls64[i00 + 1] + w01 * ls64[i01 + 1] + w10 * ls64[i10 + 1] + w11 * ls64[i11 + 1]; \
        float g2 = w00 * ls64[i00 + 2] + w01 * ls64[i01 + 2] + w10 * ls64[i10 + 2] + w11 * ls64[i11 + 2]; \
        float g3 = w00 * ls64[i00 + 3] + w01 * ls64[i01 + 3] + w10 * ls64[i10 + 3] + w11 * ls64[i11 + 3]; \
        rowg[t] = make_float4(g0, g1, g2, g3);                                        \
    }                                                                                 \
    __syncthreads();                                                                  \
    const float4 u0  = xp[ 0*256+t], u1  = xp[ 1*256+t], u2  = xp[ 2*256+t], u3  = xp[ 3*256+t]; \
    const float4 u4  = xp[ 4*256+t], u5  = xp[ 5*256+t], u6  = xp[ 6*256+t], u7  = xp[ 7*256+t]; \
    const float4 u8  = xp[ 8*256+t], u9  = xp[ 9*256+t], u10 = xp[10*256+t], u11 = xp[11*256+t]; \
    const float4 u12 = xp[12*256+t], u13 = xp[13*256+t], u14 = xp[14*256+t], u15 = xp[15*256+t]; \
    __builtin_amdgcn_sched_barrier(0);

#define GATE4(K, G0, G1, G2, G3)                                                      \
    float G0, G1, G2, G3;                                                             \
    {                                                                                 \
        float4 rg = rowg[(K) * 16 + rbase];                                           \
        float lo, hi;                                                                 \
        lo = sel4(rg.x, rg.y, rg.z, rg.w, wl0); hi = sel4(rg.x, rg.y, rg.z, rg.w, wh0); G0 = lo + fw0 * (hi - lo); \
        lo = sel4(rg.x, rg.y, rg.z, rg.w, wl1); hi = sel4(rg.x, rg.y, rg.z, rg.w, wh1); G1 = lo + fw1 * (hi - lo); \
        lo = sel4(rg.x, rg.y, rg.z, rg.w, wl2); hi = sel4(rg.x, rg.y, rg.z, rg.w, wh2); G2 = lo + fw2 * (hi - lo); \
        lo = sel4(rg.x, rg.y, rg.z, rg.w, wl3); hi = sel4(rg.x, rg.y, rg.z, rg.w, wh3); G3 = lo + fw3 * (hi - lo); \
    }

// Phase A of hist: compute 64 bin indices, pack u8x4 into 16 regs pk0..pk15.
#define PHASE_A_ALL()                                                                 \
    PKK(0,u0) PKK(1,u1) PKK(2,u2) PKK(3,u3) PKK(4,u4) PKK(5,u5) PKK(6,u6) PKK(7,u7)   \
    PKK(8,u8) PKK(9,u9) PKK(10,u10) PKK(11,u11) PKK(12,u12) PKK(13,u13) PKK(14,u14) PKK(15,u15)

#define PKK(K, U)                                                                     \
    unsigned pk##K;                                                                   \
    {                                                                                 \
        GATE4(K, g0, g1, g2, g3);                                                     \
        float p0 = U.x * g0, p1 = U.y * g1, p2 = U.z * g2, p3 = U.w * g3;             \
        int i0 = (int)floorf((p0 - vmin) * inv);                                      \
        int i1 = (int)floorf((p1 - vmin) * inv);                                      \
        int i2 = (int)floorf((p2 - vmin) * inv);                                      \
        int i3 = (int)floorf((p3 - vmin) * inv);                                      \
        i0 = min(max(i0, 0), BINS - 1); i1 = min(max(i1, 0), BINS - 1);               \
        i2 = min(max(i2, 0), BINS - 1); i3 = min(max(i3, 0), BINS - 1);               \
        pk##K = (unsigned)i0 | ((unsigned)i1 << 8) |                                  \
                ((unsigned)i2 << 16) | ((unsigned)i3 << 24);                          \
    }

// ---- K3: global min/max of x * gate (R9-proven). MUST launch with <<<512, 256>>>. ----
__global__ __launch_bounds__(256) void gated_minmax_kernel(const float* __restrict__ x,
                                                           const float* __restrict__ s,
                                                           unsigned* __restrict__ mm) {
    __shared__ float ls64[64];
    __shared__ float4 rowg[256];
    __shared__ float red[8];
    PASS_SETUP()

    float vmin = INFINITY, vmax = -INFINITY;
    #pragma unroll
    for (int it = 0; it < 4; ++it) {
        CHUNK_HEAD(it)
#define MM1(K, U)                                                                     \
        {                                                                             \
            GATE4(K, g0, g1, g2, g3);                                                 \
            float p0 = U.x * g0, p1 = U.y * g1, p2 = U.z * g2, p3 = U.w * g3;         \
            vmin = fminf(vmin, fminf(fminf(p0, p1), fminf(p2, p3)));                  \
            vmax = fmaxf(vmax, fmaxf(fmaxf(p0, p1), fmaxf(p2, p3)));                  \
        }
        MM1(0,u0) MM1(1,u1) MM1(2,u2) MM1(3,u3) MM1(4,u4) MM1(5,u5) MM1(6,u6) MM1(7,u7)
        MM1(8,u8) MM1(9,u9) MM1(10,u10) MM1(11,u11) MM1(12,u12) MM1(13,u13) MM1(14,u14) MM1(15,u15)
#undef MM1
    }

    #pragma unroll
    for (int m = 1; m <= 32; m <<= 1) {
        vmin = fminf(vmin, __shfl_xor(vmin, m));
        vmax = fmaxf(vmax, __shfl_xor(vmax, m));
    }
    const int wave = t >> 6;
    if ((t & 63) == 0) { red[wave] = vmin; red[4 + wave] = vmax; }
    __syncthreads();
    if (t == 0) {
        float m0 = fminf(fminf(red[0], red[1]), fminf(red[2], red[3]));
        float M0 = fmaxf(fmaxf(red[4], red[5]), fmaxf(red[6], red[7]));
        atomicMin(&mm[0], mapf(m0));
        atomicMax(&mm[1], mapf(M0));
    }
}

// ---- ABLATION: identical to gated_hist phase A (loads + gates + bins), NO atomics.
// pk0..pk15 pinned live via asm volatile (rule #17). 3 internal reps so the cost is
// measurable from the total-duration delta: a = (dur_us - 97.9)/3. Writes nothing.
__global__ __launch_bounds__(256) void hist_ablate_kernel(const float* __restrict__ x,
                                                          const float* __restrict__ s,
                                                          const unsigned* __restrict__ mm) {
    __shared__ float ls64[64];
    __shared__ float4 rowg[256];
    PASS_SETUP()

    const float vmin = unmapf(mm[0]);
    const float vmax = unmapf(mm[1]);
    const float inv = 128.0f / (vmax - vmin + 1e-8f);

    for (int rep = 0; rep < 3; ++rep) {
        #pragma unroll
        for (int it = 0; it < 4; ++it) {
            CHUNK_HEAD(it)
            PHASE_A_ALL()
            __builtin_amdgcn_sched_barrier(0);
            asm volatile("" :: "v"(pk0), "v"(pk1), "v"(pk2), "v"(pk3),
                              "v"(pk4), "v"(pk5), "v"(pk6), "v"(pk7),
                              "v"(pk8), "v"(pk9), "v"(pk10), "v"(pk11),
                              "v"(pk12), "v"(pk13), "v"(pk14), "v"(pk15));
        }
    }
}

// ---- K4: 128-bin histogram, phase-split (R14, best-known). <<<512, 256>>>. ----
__global__ __launch_bounds__(256) void gated_hist_kernel(const float* __restrict__ x,
                                                         const float* __restrict__ s,
                                                         const unsigned* __restrict__ mm,
                                                         unsigned* __restrict__ ghist) {
    __shared__ float ls64[64];
    __shared__ float4 rowg[256];
    __shared__ unsigned lh[BINS];
    PASS_SETUP()
    if (t < BINS) lh[t] = 0u;
    // first CHUNK_HEAD __syncthreads orders zeroing vs atomics

    const float vmin = unmapf(mm[0]);
    const float vmax = unmapf(mm[1]);
    const float inv = 128.0f / (vmax - vmin + 1e-8f);

    #pragma unroll
    for (int it = 0; it < 4; ++it) {
        CHUNK_HEAD(it)
        PHASE_A_ALL()
        __builtin_amdgcn_sched_barrier(0);
#define AT(K)                                                                         \
        atomicAdd(&lh[pk##K & 255u], 1u);                                             \
        atomicAdd(&lh[(pk##K >> 8) & 255u], 1u);                                      \
        atomicAdd(&lh[(pk##K >> 16) & 255u], 1u);                                     \
        atomicAdd(&lh[pk##K >> 24], 1u);
        AT(0) AT(1) AT(2) AT(3) AT(4) AT(5) AT(6) AT(7)
        AT(8) AT(9) AT(10) AT(11) AT(12) AT(13) AT(14) AT(15)
#undef AT
        __builtin_amdgcn_sched_barrier(0);
    }

    __syncthreads();
    if (t < BINS) {
        unsigned c = lh[t];
        if (c) atomicAdd(&ghist[t], c);
    }
}

// ---- K5: entropy ----
__global__ __launch_bounds__(64) void entropy_kernel(const unsigned* __restrict__ ghist,
                                                     float* __restrict__ out) {
    const int t = threadIdx.x;
    float c0 = (float)ghist[t];
    float c1 = (float)ghist[t + 64];
    float s = c0 + c1;
    #pragma unroll
    for (int m = 1; m <= 32; m <<= 1) s += __shfl_xor(s, m);
    const float inv = 1.0f / (s + 1e-10f);
    float p0 = c0 * inv, p1 = c1 * inv;
    float e = p0 * log2f(p0 + 1e-10f) + p1 * log2f(p1 + 1e-10f);
    #pragma unroll
    for (int m = 1; m <= 32; m <<= 1) e += __shfl_xor(e, m);
    if (t == 0) out[0] = -e;
}

extern "C" void kernel_launch(void* const* d_in, const int* in_sizes, int n_in,
                              void* d_out, int out_size, void* d_ws, size_t ws_size,
                              hipStream_t stream) {
    (void)in_sizes; (void)n_in; (void)out_size; (void)ws_size;
    const float* x  = (const float*)d_in[0];
    const float* w1 = (const float*)d_in[1];
    const float* w2 = (const float*)d_in[2];
    float* out = (float*)d_out;
    float* ws  = (float*)d_ws;

    float* p        = ws;                     // 8192
    float* s        = ws + 8192;              // 128
    unsigned* mm    = (unsigned*)(ws + 8448); // 2
    unsigned* hist  = (unsigned*)(ws + 8456); // 128

    pool_kernel<<<512, 256, 0, stream>>>(x, p);
    mid_kernel<<<1, 1024, 0, stream>>>(p, w1, w2, s, mm, hist);
    gated_minmax_kernel<<<512, 256, 0, stream>>>(x, s, mm);
    hist_ablate_kernel<<<512, 256, 0, stream>>>(x, s, mm);        // measurement only
    gated_hist_kernel<<<512, 256, 0, stream>>>(x, s, mm, hist);
    entropy_kernel<<<1, 64, 0, stream>>>(hist, out);
}

// Round 16
// 96.116 us; speedup vs baseline: 2.5085x; 2.5085x over previous
//
#include <hip/hip_runtime.h>
#include <math.h>

#define BINS 128

// ---------------- ws layout (float units) ----------------
// [0, 8192)        p       pooled means (B=2, C=64, sp=64)
// [8192, 8320)     s       sigmoid gate (2, 64)
// [8448, 8450)     mm      mapped uints {min, max}
// [8456, 8584)     ghist   uint[128]

__device__ __forceinline__ unsigned mapf(float f) {
    unsigned u = __float_as_uint(f);
    return (u & 0x80000000u) ? ~u : (u | 0x80000000u);
}
__device__ __forceinline__ float unmapf(unsigned m) {
    unsigned u = (m & 0x80000000u) ? (m & 0x7FFFFFFFu) : ~m;
    return __uint_as_float(u);
}
__device__ __forceinline__ float sel4(float g0, float g1, float g2, float g3, int k) {
    float a = (k & 1) ? g1 : g0;
    float b = (k & 1) ? g3 : g2;
    return (k & 2) ? b : a;
}
// axis coord for trilinear upsample (align_corners=False, 4 -> 64)
__device__ __forceinline__ void axgate(int v, int& lo, int& hi, float& fr) {
    float c = ((float)v + 0.5f) * 0.0625f - 0.5f;
    c = fminf(fmaxf(c, 0.0f), 3.0f);
    int l = (int)floorf(c);
    lo = l; hi = min(l + 1, 3); fr = c - (float)l;
}

// ---- K1: adaptive avg pool (R1-proven). 512 blocks, one 16x64x64 slab each. ----
__global__ __launch_bounds__(256) void pool_kernel(const float* __restrict__ x,
                                                   float* __restrict__ p) {
    const int blk = blockIdx.x;
    const int t = threadIdx.x;
    const float4* xb = (const float4*)x + (size_t)blk * 16384;
    float acc0 = 0.f, acc1 = 0.f, acc2 = 0.f, acc3 = 0.f;
    for (int n = 0; n < 64; n += 4) {
        float4 v0 = xb[(n + 0) * 256 + t]; acc0 += (v0.x + v0.y) + (v0.z + v0.w);
        float4 v1 = xb[(n + 1) * 256 + t]; acc1 += (v1.x + v1.y) + (v1.z + v1.w);
        float4 v2 = xb[(n + 2) * 256 + t]; acc2 += (v2.x + v2.y) + (v2.z + v2.w);
        float4 v3 = xb[(n + 3) * 256 + t]; acc3 += (v3.x + v3.y) + (v3.z + v3.w);
    }
    #pragma unroll
    for (int m = 0; m < 4; ++m) {
        int mask = (m == 0) ? 1 : (m == 1) ? 2 : (m == 2) ? 16 : 32;
        acc0 += __shfl_xor(acc0, mask);
        acc1 += __shfl_xor(acc1, mask);
        acc2 += __shfl_xor(acc2, mask);
        acc3 += __shfl_xor(acc3, mask);
    }
    __shared__ float red[64];
    const int lane = t & 63, wave = t >> 6;
    if (lane < 16 && (lane & 3) == 0) {
        const int pw = lane >> 2;
        red[(0 * 4 + pw) * 4 + wave] = acc0;
        red[(1 * 4 + pw) * 4 + wave] = acc1;
        red[(2 * 4 + pw) * 4 + wave] = acc2;
        red[(3 * 4 + pw) * 4 + wave] = acc3;
    }
    __syncthreads();
    if (t < 16)
        p[blk * 16 + t] = (red[t * 4 + 0] + red[t * 4 + 1] + red[t * 4 + 2] + red[t * 4 + 3]) * (1.0f / 4096.0f);
}

// ---- K2: w1 conv + InstanceNorm + GELU + w2 conv + sigmoid + init (R1-proven) ----
__global__ __launch_bounds__(1024) void mid_kernel(const float* __restrict__ p,
                                                   const float* __restrict__ w1,
                                                   const float* __restrict__ w2,
                                                   float* __restrict__ s_out,
                                                   unsigned* __restrict__ mm,
                                                   unsigned* __restrict__ hist) {
    __shared__ float hs[2 * 8 * 64];
    const int t = threadIdx.x;
    const int b = t >> 9, cm = (t >> 6) & 7, sp = t & 63;
    float h = 0.f;
    const float* pb = p + b * 64 * 64 + sp;
    const float* w1r = w1 + cm * 64;
    for (int c = 0; c < 64; ++c) h += w1r[c] * pb[c * 64];
    float s1 = h;
    #pragma unroll
    for (int m = 1; m <= 32; m <<= 1) s1 += __shfl_xor(s1, m);
    const float mu = s1 * (1.0f / 64.0f);
    float d = h - mu;
    float s2 = d * d;
    #pragma unroll
    for (int m = 1; m <= 32; m <<= 1) s2 += __shfl_xor(s2, m);
    const float var = s2 * (1.0f / 64.0f);
    const float hn = d / sqrtf(var + 1e-5f);
    hs[(b * 8 + cm) * 64 + sp] = 0.5f * hn * (1.0f + erff(hn * 0.70710678118654752440f));
    __syncthreads();
    if (t < 128) {
        const int bb = t >> 6, ss = t & 63;
        float acc = 0.f;
        #pragma unroll
        for (int c = 0; c < 8; ++c) acc += w2[c] * hs[(bb * 8 + c) * 64 + ss];
        s_out[t] = 1.0f / (1.0f + expf(-acc));
    }
    if (t == 0) { mm[0] = 0xFFFFFFFFu; mm[1] = 0u; }
    if (t >= 128 && t < 256) hist[t - 128] = 0u;
}

// ---------- barrier-free streaming skeleton (R15 ablation-driven) ----------
// 512 blocks, 4 chunks/block (one (b,c) quarter-slab = 16 d-slices).
// rowg_all[1024] = bilinear(d,h) gate at 4 w-corners for ALL 16 d x 64 h rows,
// built ONCE per pass; the 4-chunk main loop then has ZERO barriers, so waves
// overlap loads/compute across chunks freely.

#define PASS_SETUP2()                                                                 \
    const int t = threadIdx.x;                                                        \
    const int bid = blockIdx.x;                                                       \
    const int cbase = (bid & 7) * 256 + (bid >> 3) * 4;                               \
    const int b = cbase >> 10;                                                        \
    if (t < 64) ls64[t] = s[b * 64 + t];                                              \
    int wl0, wh0, wl1, wh1, wl2, wh2, wl3, wh3;                                       \
    float fw0, fw1, fw2, fw3;                                                         \
    {                                                                                 \
        const int wb = (t & 15) * 4;                                                  \
        axgate(wb + 0, wl0, wh0, fw0); axgate(wb + 1, wl1, wh1, fw1);                 \
        axgate(wb + 2, wl2, wh2, fw2); axgate(wb + 3, wl3, wh3, fw3);                 \
    }                                                                                 \
    const int rbase = t >> 4;                                                         \
    __syncthreads();                                                                  \
    _Pragma("unroll")                                                                 \
    for (int k = 0; k < 4; ++k) {                                                     \
        const int e = k * 256 + t;                                                    \
        const int dloc = e >> 6, hh_ = e & 63;                                        \
        int dl, dh2; float fd; axgate((cbase & 15) * 4 + dloc, dl, dh2, fd);          \
        int hl, hh3; float fh; axgate(hh_, hl, hh3, fh);                              \
        const float w00 = (1.f - fd) * (1.f - fh), w01 = (1.f - fd) * fh;             \
        const float w10 = fd * (1.f - fh), w11 = fd * fh;                             \
        const int i00 = dl * 16 + hl * 4, i01 = dl * 16 + hh3 * 4;                    \
        const int i10 = dh2 * 16 + hl * 4, i11 = dh2 * 16 + hh3 * 4;                  \
        rowg[e] = make_float4(                                                        \
            w00 * ls64[i00 + 0] + w01 * ls64[i01 + 0] + w10 * ls64[i10 + 0] + w11 * ls64[i11 + 0], \
            w00 * ls64[i00 + 1] + w01 * ls64[i01 + 1] + w10 * ls64[i10 + 1] + w11 * ls64[i11 + 1], \
            w00 * ls64[i00 + 2] + w01 * ls64[i01 + 2] + w10 * ls64[i10 + 2] + w11 * ls64[i11 + 2], \
            w00 * ls64[i00 + 3] + w01 * ls64[i01 + 3] + w10 * ls64[i10 + 3] + w11 * ls64[i11 + 3]);\
    }                                                                                 \
    __syncthreads();

#define LOADS16(IT)                                                                   \
    const float4* xp = (const float4*)x + (size_t)(cbase + (IT)) * 4096;              \
    const float4 u0  = xp[ 0*256+t], u1  = xp[ 1*256+t], u2  = xp[ 2*256+t], u3  = xp[ 3*256+t]; \
    const float4 u4  = xp[ 4*256+t], u5  = xp[ 5*256+t], u6  = xp[ 6*256+t], u7  = xp[ 7*256+t]; \
    const float4 u8  = xp[ 8*256+t], u9  = xp[ 9*256+t], u10 = xp[10*256+t], u11 = xp[11*256+t]; \
    const float4 u12 = xp[12*256+t], u13 = xp[13*256+t], u14 = xp[14*256+t], u15 = xp[15*256+t]; \
    __builtin_amdgcn_sched_barrier(0);

// gate for load K of chunk IT: row = IT*256 + K*16 + rbase (verified mapping)
#define GATE4A(IT, K, G0, G1, G2, G3)                                                 \
    float G0, G1, G2, G3;                                                             \
    {                                                                                 \
        float4 rg = rowg[(IT) * 256 + (K) * 16 + rbase];                              \
        float lo, hi;                                                                 \
        lo = sel4(rg.x, rg.y, rg.z, rg.w, wl0); hi = sel4(rg.x, rg.y, rg.z, rg.w, wh0); G0 = lo + fw0 * (hi - lo); \
        lo = sel4(rg.x, rg.y, rg.z, rg.w, wl1); hi = sel4(rg.x, rg.y, rg.z, rg.w, wh1); G1 = lo + fw1 * (hi - lo); \
        lo = sel4(rg.x, rg.y, rg.z, rg.w, wl2); hi = sel4(rg.x, rg.y, rg.z, rg.w, wh2); G2 = lo + fw2 * (hi - lo); \
        lo = sel4(rg.x, rg.y, rg.z, rg.w, wl3); hi = sel4(rg.x, rg.y, rg.z, rg.w, wh3); G3 = lo + fw3 * (hi - lo); \
    }

// ---- K3: global min/max of x * gate, barrier-free. MUST launch <<<512, 256>>>. ----
__global__ __launch_bounds__(256) void gated_minmax_kernel(const float* __restrict__ x,
                                                           const float* __restrict__ s,
                                                           unsigned* __restrict__ mm) {
    __shared__ float ls64[64];
    __shared__ float4 rowg[1024];   // 16 KB
    __shared__ float red[8];
    PASS_SETUP2()

    float vmin = INFINITY, vmax = -INFINITY;
    #pragma unroll
    for (int it = 0; it < 4; ++it) {
        LOADS16(it)
#define MM1(K, U)                                                                     \
        {                                                                             \
            GATE4A(it, K, g0, g1, g2, g3);                                            \
            float p0 = U.x * g0, p1 = U.y * g1, p2 = U.z * g2, p3 = U.w * g3;         \
            vmin = fminf(vmin, fminf(fminf(p0, p1), fminf(p2, p3)));                  \
            vmax = fmaxf(vmax, fmaxf(fmaxf(p0, p1), fmaxf(p2, p3)));                  \
        }
        MM1(0,u0) MM1(1,u1) MM1(2,u2) MM1(3,u3) MM1(4,u4) MM1(5,u5) MM1(6,u6) MM1(7,u7)
        MM1(8,u8) MM1(9,u9) MM1(10,u10) MM1(11,u11) MM1(12,u12) MM1(13,u13) MM1(14,u14) MM1(15,u15)
#undef MM1
    }

    #pragma unroll
    for (int m = 1; m <= 32; m <<= 1) {
        vmin = fminf(vmin, __shfl_xor(vmin, m));
        vmax = fmaxf(vmax, __shfl_xor(vmax, m));
    }
    const int wave = t >> 6;
    __syncthreads();
    if ((t & 63) == 0) { red[wave] = vmin; red[4 + wave] = vmax; }
    __syncthreads();
    if (t == 0) {
        float m0 = fminf(fminf(red[0], red[1]), fminf(red[2], red[3]));
        float M0 = fmaxf(fmaxf(red[4], red[5]), fmaxf(red[6], red[7]));
        atomicMin(&mm[0], mapf(m0));
        atomicMax(&mm[1], mapf(M0));
    }
}

// ---- K4: 128-bin histogram, barrier-free skeleton + phase-split atomics. ----
// MUST launch with <<<512, 256>>>.
__global__ __launch_bounds__(256) void gated_hist_kernel(const float* __restrict__ x,
                                                         const float* __restrict__ s,
                                                         const unsigned* __restrict__ mm,
                                                         unsigned* __restrict__ ghist) {
    __shared__ float ls64[64];
    __shared__ float4 rowg[1024];   // 16 KB
    __shared__ unsigned lh[BINS];
    if (threadIdx.x < BINS) lh[threadIdx.x] = 0u;   // before PASS_SETUP2's barrier
    PASS_SETUP2()

    const float vmin = unmapf(mm[0]);
    const float vmax = unmapf(mm[1]);
    const float inv = 128.0f / (vmax - vmin + 1e-8f);

    #pragma unroll
    for (int it = 0; it < 4; ++it) {
        LOADS16(it)
        // phase A: 64 bin indices packed u8x4 into 16 regs
#define PKK(K, U)                                                                     \
        unsigned pk##K;                                                               \
        {                                                                             \
            GATE4A(it, K, g0, g1, g2, g3);                                            \
            float p0 = U.x * g0, p1 = U.y * g1, p2 = U.z * g2, p3 = U.w * g3;         \
            int i0 = (int)floorf((p0 - vmin) * inv);                                  \
            int i1 = (int)floorf((p1 - vmin) * inv);                                  \
            int i2 = (int)floorf((p2 - vmin) * inv);                                  \
            int i3 = (int)floorf((p3 - vmin) * inv);                                  \
            i0 = min(max(i0, 0), BINS - 1); i1 = min(max(i1, 0), BINS - 1);           \
            i2 = min(max(i2, 0), BINS - 1); i3 = min(max(i3, 0), BINS - 1);           \
            pk##K = (unsigned)i0 | ((unsigned)i1 << 8) |                              \
                    ((unsigned)i2 << 16) | ((unsigned)i3 << 24);                      \
        }
        PKK(0,u0) PKK(1,u1) PKK(2,u2) PKK(3,u3) PKK(4,u4) PKK(5,u5) PKK(6,u6) PKK(7,u7)
        PKK(8,u8) PKK(9,u9) PKK(10,u10) PKK(11,u11) PKK(12,u12) PKK(13,u13) PKK(14,u14) PKK(15,u15)
#undef PKK
        __builtin_amdgcn_sched_barrier(0);
        // phase B: 64 back-to-back LDS atomics
#define AT(K)                                                                         \
        atomicAdd(&lh[pk##K & 255u], 1u);                                             \
        atomicAdd(&lh[(pk##K >> 8) & 255u], 1u);                                      \
        atomicAdd(&lh[(pk##K >> 16) & 255u], 1u);                                     \
        atomicAdd(&lh[pk##K >> 24], 1u);
        AT(0) AT(1) AT(2) AT(3) AT(4) AT(5) AT(6) AT(7)
        AT(8) AT(9) AT(10) AT(11) AT(12) AT(13) AT(14) AT(15)
#undef AT
        __builtin_amdgcn_sched_barrier(0);
    }

    __syncthreads();
    if (t < BINS) {
        unsigned c = lh[t];
        if (c) atomicAdd(&ghist[t], c);
    }
}

// ---- K5: entropy ----
__global__ __launch_bounds__(64) void entropy_kernel(const unsigned* __restrict__ ghist,
                                                     float* __restrict__ out) {
    const int t = threadIdx.x;
    float c0 = (float)ghist[t];
    float c1 = (float)ghist[t + 64];
    float s = c0 + c1;
    #pragma unroll
    for (int m = 1; m <= 32; m <<= 1) s += __shfl_xor(s, m);
    const float inv = 1.0f / (s + 1e-10f);
    float p0 = c0 * inv, p1 = c1 * inv;
    float e = p0 * log2f(p0 + 1e-10f) + p1 * log2f(p1 + 1e-10f);
    #pragma unroll
    for (int m = 1; m <= 32; m <<= 1) e += __shfl_xor(e, m);
    if (t == 0) out[0] = -e;
}

extern "C" void kernel_launch(void* const* d_in, const int* in_sizes, int n_in,
                              void* d_out, int out_size, void* d_ws, size_t ws_size,
                              hipStream_t stream) {
    (void)in_sizes; (void)n_in; (void)out_size; (void)ws_size;
    const float* x  = (const float*)d_in[0];
    const float* w1 = (const float*)d_in[1];
    const float* w2 = (const float*)d_in[2];
    float* out = (float*)d_out;
    float* ws  = (float*)d_ws;

    float* p        = ws;                     // 8192
    float* s        = ws + 8192;              // 128
    unsigned* mm    = (unsigned*)(ws + 8448); // 2
    unsigned* hist  = (unsigned*)(ws + 8456); // 128

    pool_kernel<<<512, 256, 0, stream>>>(x, p);
    mid_kernel<<<1, 1024, 0, stream>>>(p, w1, w2, s, mm, hist);
    gated_minmax_kernel<<<512, 256, 0, stream>>>(x, s, mm);
    gated_hist_kernel<<<512, 256, 0, stream>>>(x, s, mm, hist);
    entropy_kernel<<<1, 64, 0, stream>>>(hist, out);
}